// Round 12
// baseline (213.746 us; speedup 1.0000x reference)
//
#include <hip/hip_runtime.h>
#include <hip/hip_bf16.h>

typedef __attribute__((ext_vector_type(8))) short bf16x8;
typedef __attribute__((ext_vector_type(4))) float f32x4;

#define L_SEQ 512
#define N_IN 12
#define S_DIM 128
#define M_OUT 12
#define LPAD 40           // shorts per n-row (80B -> <=2-way banks)
#define KT_STRIDE (16*LPAD)

// RNE f32->bf16 (cold paths)
__device__ inline short f2bf(float f) {
    union { float f; unsigned u; } q; q.f = f;
    unsigned r = (q.u + 0x7fffu + ((q.u >> 16) & 1u)) >> 16;
    return (short)r;
}
// packed f32x2 -> 2xbf16 (RNE), one VALU op
__device__ inline unsigned cvtpk(float lo, float hi) {
    unsigned r;
    asm("v_cvt_pk_bf16_f32 %0, %1, %2" : "=v"(r) : "v"(lo), "v"(hi));
    return r;
}
// B-slot (kt,q,j) holds state row s = 32kt + 16(j>>2) + 4q + (j&3).
// Same-lane D->B chaining: E2E-verified R4/R5/R7/R8/R11.
__device__ inline int s_perm(int kt, int q, int j) {
    return 32 * kt + 16 * (j >> 2) + 4 * q + (j & 3);
}
// lgkm-only barrier: does NOT drain vmcnt (helpers' x prefetch stays in flight)
__device__ inline void block_sync() {
    asm volatile("s_waitcnt lgkmcnt(0)" ::: "memory");
    __builtin_amdgcn_s_barrier();
}

__global__ __launch_bounds__(512, 1)
void elman_kernel(const float* __restrict__ x,
                  const float* __restrict__ a0,
                  const float* __restrict__ U_w,
                  const float* __restrict__ U_b,
                  const float* __restrict__ W_w,
                  const float* __restrict__ W_b,
                  const float* __restrict__ V_w,
                  const float* __restrict__ V_b,
                  float* __restrict__ out)
{
    __shared__ __align__(16) short stx[2][2][4 * KT_STRIDE];  // [tile][buf]
    __shared__ __align__(16) short xr[2][4][64 * 8];          // [tile][slot]

    const int tid  = threadIdx.x;
    const int w    = tid >> 6;        // waves 0..3 compute (both tiles), 4..7 helpers
    const int l    = tid & 63;
    const int n    = l & 15;
    const int q    = l >> 4;
    const bool qodd = (q & 1);
    const int b0   = blockIdx.x * 32; // tile A rows b0..b0+15, tile B rows b0+16..b0+31
    const int fragoff = n * LPAD + q * 8;
    const int h    = w & 3;           // helper id

    const float* xp0_lo = x + (size_t)(b0 + n) * L_SEQ * N_IN + (q & 1) * 8;
    const float* xp0_hi = xp0_lo + (qodd ? 0 : 4);
    const float* xp1_lo = x + (size_t)(b0 + 16 + n) * L_SEQ * N_IN + (q & 1) * 8;
    const float* xp1_hi = xp1_lo + (qodd ? 0 : 4);

#define MAKE_XF(XF, XA, XB) do {                                                       \
    union { unsigned uu[4]; bf16x8 v; } xu_;                                           \
    xu_.uu[0] = cvtpk(XA.x, XA.y);                                                     \
    xu_.uu[1] = cvtpk(XA.z, XA.w);                                                     \
    xu_.uu[2] = qodd ? 0x00003F80u : cvtpk(XB.x, XB.y);  /* k==12 -> bf16(1.0) */      \
    xu_.uu[3] = qodd ? 0u          : cvtpk(XB.z, XB.w);                                \
    XF = xu_.v;                                                                        \
} while (0)

    // ---- step-invariant fragments (compute waves; SHARED across both tiles) ----
    bf16x8 wf[2][4]; bf16x8 uf[2];
    if (w < 4) {
        #pragma unroll
        for (int hh = 0; hh < 2; ++hh) {
            const int c = (2 * w + hh) * 16 + n;
            #pragma unroll
            for (int li = 0; li < 4; ++li) {
                const int kt = (w + li) & 3;
                #pragma unroll
                for (int j = 0; j < 8; ++j)
                    wf[hh][li][j] = f2bf(W_w[(size_t)s_perm(kt, q, j) * S_DIM + c]);
            }
            #pragma unroll
            for (int j = 0; j < 8; ++j) {
                const int k = q * 8 + j;
                float v;
                if (k < N_IN)       v = U_w[(size_t)k * S_DIM + c];
                else if (k == N_IN) v = W_b[c] + U_b[c];   // bias via x-slot k=12 == 1.0
                else                v = 0.f;
                uf[hh][j] = f2bf(v);
            }
        }
    }

    // ---- stage a0 for both tiles into stx[ti][0] ----
    for (int idx = tid; idx < 2 * 4 * 16 * 32; idx += 512) {
        const int ti = idx >> 11, rem = idx & 2047;
        const int kt = rem >> 9, r = (rem >> 5) & 15, qj = rem & 31;
        const int s = s_perm(kt, qj >> 3, qj & 7);
        stx[ti][0][kt * KT_STRIDE + r * LPAD + qj] =
            f2bf(a0[(size_t)(b0 + ti * 16 + r) * S_DIM + s]);
    }

    // ---- helper prologue: prestage xf(0..2) both tiles; init in-flight pairs ----
    float4 p0A, p0B, p1A, p1B;
    if (w >= 4) {
        if (h < 3) {
            float4 sa = *(const float4*)(xp0_lo + (size_t)h * N_IN);
            float4 sb = *(const float4*)(xp0_hi + (size_t)h * N_IN);
            bf16x8 xf; MAKE_XF(xf, sa, sb);
            *(bf16x8*)&xr[0][h][l * 8] = xf;
            sa = *(const float4*)(xp1_lo + (size_t)h * N_IN);
            sb = *(const float4*)(xp1_hi + (size_t)h * N_IN);
            MAKE_XF(xf, sa, sb);
            *(bf16x8*)&xr[1][h][l * 8] = xf;
        }
        const int t0 = (h == 3) ? 3 : (h + 4);
        p0A = *(const float4*)(xp0_lo + (size_t)t0 * N_IN);
        p0B = *(const float4*)(xp0_hi + (size_t)t0 * N_IN);
        p1A = *(const float4*)(xp1_lo + (size_t)t0 * N_IN);
        p1B = *(const float4*)(xp1_hi + (size_t)t0 * N_IN);
    }
    block_sync();

    // ---- compute prologue ----
    bf16x8 st0Own, st0f1, st0f2, st0f3, xfc0_cur, xfc0_next;
    bf16x8 st1Own, st1f1, st1f2, st1f3, xfc1_cur, xfc1_next;
    f32x4 aU00, aU01, aU10, aU11;     // accU[tile][h]
    if (w < 4) {
        const short* rd0 = &stx[0][0][0];
        st0Own = *(const bf16x8*)&rd0[((w + 0) & 3) * KT_STRIDE + fragoff];
        st0f1  = *(const bf16x8*)&rd0[((w + 1) & 3) * KT_STRIDE + fragoff];
        st0f2  = *(const bf16x8*)&rd0[((w + 2) & 3) * KT_STRIDE + fragoff];
        st0f3  = *(const bf16x8*)&rd0[((w + 3) & 3) * KT_STRIDE + fragoff];
        const short* rd1 = &stx[1][0][0];
        st1Own = *(const bf16x8*)&rd1[((w + 0) & 3) * KT_STRIDE + fragoff];
        st1f1  = *(const bf16x8*)&rd1[((w + 1) & 3) * KT_STRIDE + fragoff];
        st1f2  = *(const bf16x8*)&rd1[((w + 2) & 3) * KT_STRIDE + fragoff];
        st1f3  = *(const bf16x8*)&rd1[((w + 3) & 3) * KT_STRIDE + fragoff];
        bf16x8 xf00 = *(const bf16x8*)&xr[0][0][l * 8];
        xfc0_cur    = *(const bf16x8*)&xr[0][1][l * 8];
        xfc0_next   = *(const bf16x8*)&xr[0][2][l * 8];
        bf16x8 xf10 = *(const bf16x8*)&xr[1][0][l * 8];
        xfc1_cur    = *(const bf16x8*)&xr[1][1][l * 8];
        xfc1_next   = *(const bf16x8*)&xr[1][2][l * 8];
        f32x4 z = {0.f, 0.f, 0.f, 0.f};
        aU00 = __builtin_amdgcn_mfma_f32_16x16x32_bf16(uf[0], xf00, z, 0, 0, 0);
        aU01 = __builtin_amdgcn_mfma_f32_16x16x32_bf16(uf[1], xf00, z, 0, 0, 0);
        aU10 = __builtin_amdgcn_mfma_f32_16x16x32_bf16(uf[0], xf10, z, 0, 0, 0);
        aU11 = __builtin_amdgcn_mfma_f32_16x16x32_bf16(uf[1], xf10, z, 0, 0, 0);
    }

    // ---- per-tile step body: 4 independent 1-deep chains; accU(t) enters as
    //      C-init of the LAST W-MFMA (computed a full step earlier -> no stall) ----
#define BODY(TI, STOWN, STF1, STF2, STF3, XCUR, XNEXT, AU0, AU1, TT) do {              \
    f32x4 z_ = {0.f, 0.f, 0.f, 0.f};                                                   \
    f32x4 nU0 = __builtin_amdgcn_mfma_f32_16x16x32_bf16(uf[0], XCUR, z_, 0, 0, 0);     \
    f32x4 nU1 = __builtin_amdgcn_mfma_f32_16x16x32_bf16(uf[1], XCUR, z_, 0, 0, 0);     \
    f32x4 c00 = __builtin_amdgcn_mfma_f32_16x16x32_bf16(wf[0][0], STOWN, z_, 0, 0, 0); \
    f32x4 c10 = __builtin_amdgcn_mfma_f32_16x16x32_bf16(wf[1][0], STOWN, z_, 0, 0, 0); \
    f32x4 c01 = __builtin_amdgcn_mfma_f32_16x16x32_bf16(wf[0][1], STF1, z_, 0, 0, 0);  \
    f32x4 c11 = __builtin_amdgcn_mfma_f32_16x16x32_bf16(wf[1][1], STF1, z_, 0, 0, 0);  \
    f32x4 c02 = __builtin_amdgcn_mfma_f32_16x16x32_bf16(wf[0][2], STF2, z_, 0, 0, 0);  \
    f32x4 c12 = __builtin_amdgcn_mfma_f32_16x16x32_bf16(wf[1][2], STF2, z_, 0, 0, 0);  \
    f32x4 c03 = __builtin_amdgcn_mfma_f32_16x16x32_bf16(wf[0][3], STF3, AU0, 0, 0, 0); \
    f32x4 c13 = __builtin_amdgcn_mfma_f32_16x16x32_bf16(wf[1][3], STF3, AU1, 0, 0, 0); \
    AU0 = nU0; AU1 = nU1;                                                              \
    f32x4 s0 = (c00 + c01) + (c02 + c03);                                              \
    f32x4 s1 = (c10 + c11) + (c12 + c13);                                              \
    union { unsigned uu[4]; bf16x8 v; } su;                                            \
    su.uu[0] = cvtpk(fmaxf(s0[0], 0.f), fmaxf(s0[1], 0.f));                            \
    su.uu[1] = cvtpk(fmaxf(s0[2], 0.f), fmaxf(s0[3], 0.f));                            \
    su.uu[2] = cvtpk(fmaxf(s1[0], 0.f), fmaxf(s1[1], 0.f));                            \
    su.uu[3] = cvtpk(fmaxf(s1[2], 0.f), fmaxf(s1[3], 0.f));                            \
    STOWN = su.v;                                                                      \
    *(bf16x8*)&stx[TI][((TT) + 1) & 1][w * KT_STRIDE + fragoff] = STOWN;               \
    XCUR = XNEXT;                                                                      \
} while (0)

#define STEP(UU) do {                                                                  \
    const int tt = t + (UU);                                                           \
    if (w < 4) {                                                                       \
        __builtin_amdgcn_s_setprio(1);                                                 \
        BODY(0, st0Own, st0f1, st0f2, st0f3, xfc0_cur, xfc0_next, aU00, aU01, tt);     \
        BODY(1, st1Own, st1f1, st1f2, st1f3, xfc1_cur, xfc1_next, aU10, aU11, tt);     \
        __builtin_amdgcn_s_setprio(0);                                                 \
    } else if (h == (((UU) + 3) & 3)) {                                                \
        bf16x8 xf_;                                                                    \
        MAKE_XF(xf_, p0A, p0B);                                                        \
        *(bf16x8*)&xr[0][h][l * 8] = xf_;                                              \
        MAKE_XF(xf_, p1A, p1B);                                                        \
        *(bf16x8*)&xr[1][h][l * 8] = xf_;                                              \
        const int s2_ = (tt + 7 < L_SEQ) ? (tt + 7) : (L_SEQ - 1);                     \
        p0A = *(const float4*)(xp0_lo + (size_t)s2_ * N_IN);                           \
        p0B = *(const float4*)(xp0_hi + (size_t)s2_ * N_IN);                           \
        p1A = *(const float4*)(xp1_lo + (size_t)s2_ * N_IN);                           \
        p1B = *(const float4*)(xp1_hi + (size_t)s2_ * N_IN);                           \
    }                                                                                  \
    block_sync();                                                                      \
    if (w < 4) {                                                                       \
        const short* rd0_ = &stx[0][(tt + 1) & 1][0];                                  \
        st0f1 = *(const bf16x8*)&rd0_[((w + 1) & 3) * KT_STRIDE + fragoff];            \
        st0f2 = *(const bf16x8*)&rd0_[((w + 2) & 3) * KT_STRIDE + fragoff];            \
        st0f3 = *(const bf16x8*)&rd0_[((w + 3) & 3) * KT_STRIDE + fragoff];            \
        const short* rd1_ = &stx[1][(tt + 1) & 1][0];                                  \
        st1f1 = *(const bf16x8*)&rd1_[((w + 1) & 3) * KT_STRIDE + fragoff];            \
        st1f2 = *(const bf16x8*)&rd1_[((w + 2) & 3) * KT_STRIDE + fragoff];            \
        st1f3 = *(const bf16x8*)&rd1_[((w + 3) & 3) * KT_STRIDE + fragoff];            \
        xfc0_next = *(const bf16x8*)&xr[0][(((UU) + 3) & 3)][l * 8];                   \
        xfc1_next = *(const bf16x8*)&xr[1][(((UU) + 3) & 3)][l * 8];                   \
    }                                                                                  \
} while (0)

    for (int t = 0; t < L_SEQ; t += 4) {
        STEP(0);
        STEP(1);
        STEP(2);
        STEP(3);
    }
#undef STEP
#undef BODY
#undef MAKE_XF

    // ---- epilogue: wave 0 -> tile A, wave 1 -> tile B.
    //      frag li holds physical k-tile kt=(w+li)&3 of that wave's tile. ----
    if (w < 2) {
        const bf16x8 fr0 = (w == 0) ? st0Own : st1Own;
        const bf16x8 fr1 = (w == 0) ? st0f1  : st1f1;
        const bf16x8 fr2 = (w == 0) ? st0f2  : st1f2;
        const bf16x8 fr3 = (w == 0) ? st0f3  : st1f3;
        f32x4 acc = {0.f, 0.f, 0.f, 0.f};
        #pragma unroll
        for (int li = 0; li < 4; ++li) {
            const int kt = (w + li) & 3;
            bf16x8 vf;
            #pragma unroll
            for (int j = 0; j < 8; ++j)
                vf[j] = (n < M_OUT)
                      ? f2bf(V_w[(size_t)s_perm(kt, q, j) * M_OUT + n])
                      : (short)0;
            const bf16x8 stt = (li == 0) ? fr0 : (li == 1) ? fr1 : (li == 2) ? fr2 : fr3;
            acc = __builtin_amdgcn_mfma_f32_16x16x32_bf16(vf, stt, acc, 0, 0, 0);
        }
        #pragma unroll
        for (int j = 0; j < 4; ++j) {
            const int m = 4 * q + j;
            if (m < M_OUT)
                out[(size_t)(b0 + w * 16 + n) * M_OUT + m] = acc[j] + V_b[m];
        }
    }
}

extern "C" void kernel_launch(void* const* d_in, const int* in_sizes, int n_in,
                              void* d_out, int out_size, void* d_ws, size_t ws_size,
                              hipStream_t stream) {
    const float* x   = (const float*)d_in[0];
    const float* a0  = (const float*)d_in[1];
    const float* U_w = (const float*)d_in[2];
    const float* U_b = (const float*)d_in[3];
    const float* W_w = (const float*)d_in[4];
    const float* W_b = (const float*)d_in[5];
    const float* V_w = (const float*)d_in[6];
    const float* V_b = (const float*)d_in[7];
    float* out = (float*)d_out;

    hipLaunchKernelGGL(elman_kernel, dim3(4096 / 32), dim3(512), 0, stream,
                       x, a0, U_w, U_b, W_w, W_b, V_w, V_b, out);
}

// Round 13
// 146.000 us; speedup vs baseline: 1.4640x; 1.4640x over previous
//
#include <hip/hip_runtime.h>
#include <hip/hip_bf16.h>

typedef __attribute__((ext_vector_type(8))) short bf16x8;
typedef __attribute__((ext_vector_type(4))) float f32x4;

#define L_SEQ 512
#define N_IN 12
#define S_DIM 128
#define M_OUT 12
#define LPAD 40           // shorts per n-row (80B -> <=2-way banks)
#define KT_STRIDE (16*LPAD)

// RNE f32->bf16 (cold paths)
__device__ inline short f2bf(float f) {
    union { float f; unsigned u; } q; q.f = f;
    unsigned r = (q.u + 0x7fffu + ((q.u >> 16) & 1u)) >> 16;
    return (short)r;
}
// packed f32x2 -> 2xbf16 (RNE), one VALU op
__device__ inline unsigned cvtpk(float lo, float hi) {
    unsigned r;
    asm("v_cvt_pk_bf16_f32 %0, %1, %2" : "=v"(r) : "v"(lo), "v"(hi));
    return r;
}
// B-slot (kt,q,j) holds state row s = 32kt + 16(j>>2) + 4q + (j&3).
// Same-lane D->B chaining: E2E-verified R4/R5/R7/R8/R11.
__device__ inline int s_perm(int kt, int q, int j) {
    return 32 * kt + 16 * (j >> 2) + 4 * q + (j & 3);
}
// lgkm-only barrier: does NOT drain vmcnt (x prefetch loads stay in flight)
__device__ inline void block_sync() {
    asm volatile("s_waitcnt lgkmcnt(0)" ::: "memory");
    __builtin_amdgcn_s_barrier();
}

__global__ __launch_bounds__(256, 1)
void elman_kernel(const float* __restrict__ x,
                  const float* __restrict__ a0,
                  const float* __restrict__ U_w,
                  const float* __restrict__ U_b,
                  const float* __restrict__ W_w,
                  const float* __restrict__ W_b,
                  const float* __restrict__ V_w,
                  const float* __restrict__ V_b,
                  float* __restrict__ out)
{
    __shared__ __align__(16) short stx[2][4 * KT_STRIDE];  // state exchange (ping-pong)

    const int tid  = threadIdx.x;
    const int w    = tid >> 6;        // 4 compute waves, one per SIMD
    const int l    = tid & 63;
    const int n    = l & 15;
    const int q    = l >> 4;
    const bool qodd = (q & 1);
    const int b0   = blockIdx.x * 16;
    const int row  = b0 + n;
    const int fragoff = n * LPAD + q * 8;

    const float* xpA = x + (size_t)row * L_SEQ * N_IN + (q & 1) * 8;
    const float* xpB = xpA + (qodd ? 0 : 4);

#define MAKE_XF(XF, XA, XB) do {                                                       \
    union { unsigned uu[4]; bf16x8 v; } xu_;                                           \
    xu_.uu[0] = cvtpk(XA.x, XA.y);                                                     \
    xu_.uu[1] = cvtpk(XA.z, XA.w);                                                     \
    xu_.uu[2] = qodd ? 0x00003F80u : cvtpk(XB.x, XB.y);  /* k==12 -> bf16(1.0) */      \
    xu_.uu[3] = qodd ? 0u          : cvtpk(XB.z, XB.w);                                \
    XF = xu_.v;                                                                        \
} while (0)

    // ---- step-invariant fragments: wave w owns output s-rows [32w,32w+32) ----
    bf16x8 wf[2][4]; bf16x8 uf[2];
    #pragma unroll
    for (int hh = 0; hh < 2; ++hh) {
        const int c = (2 * w + hh) * 16 + n;
        #pragma unroll
        for (int li = 0; li < 4; ++li) {
            const int kt = (w + li) & 3;
            #pragma unroll
            for (int j = 0; j < 8; ++j)
                wf[hh][li][j] = f2bf(W_w[(size_t)s_perm(kt, q, j) * S_DIM + c]);
        }
        #pragma unroll
        for (int j = 0; j < 8; ++j) {
            const int k = q * 8 + j;
            float v;
            if (k < N_IN)       v = U_w[(size_t)k * S_DIM + c];
            else if (k == N_IN) v = W_b[c] + U_b[c];   // bias via x-slot k=12 == 1.0
            else                v = 0.f;
            uf[hh][j] = f2bf(v);
        }
    }

    // ---- stage a0 into stx[0] (exchange layout) ----
    for (int idx = tid; idx < 4 * 16 * 32; idx += 256) {
        const int kt = idx >> 9, r = (idx >> 5) & 15, qj = idx & 31;
        const int s = s_perm(kt, qj >> 3, qj & 7);
        stx[0][kt * KT_STRIDE + r * LPAD + qj] = f2bf(a0[(size_t)(b0 + r) * S_DIM + s]);
    }

    // ---- x prologue: temps x(0),x(1); rotation slots 2,3,0,1 = x(2),x(3),x(4),x(5) ----
    float4 t0A = *(const float4*)(xpA + 0 * N_IN), t0B = *(const float4*)(xpB + 0 * N_IN);
    float4 t1A = *(const float4*)(xpA + 1 * N_IN), t1B = *(const float4*)(xpB + 1 * N_IN);
    float4 xa2 = *(const float4*)(xpA + 2 * N_IN), xb2 = *(const float4*)(xpB + 2 * N_IN);
    float4 xa3 = *(const float4*)(xpA + 3 * N_IN), xb3 = *(const float4*)(xpB + 3 * N_IN);
    float4 xa0 = *(const float4*)(xpA + 4 * N_IN), xb0 = *(const float4*)(xpB + 4 * N_IN);
    float4 xa1 = *(const float4*)(xpA + 5 * N_IN), xb1 = *(const float4*)(xpB + 5 * N_IN);

    bf16x8 xfc;                       // xf(t+1) entering body t
    f32x4 accU0, accU1;               // U.x(t) + bias, entering body t
    {
        bf16x8 xf0; MAKE_XF(xf0, t0A, t0B);
        f32x4 z = {0.f, 0.f, 0.f, 0.f};
        accU0 = __builtin_amdgcn_mfma_f32_16x16x32_bf16(uf[0], xf0, z, 0, 0, 0);
        accU1 = __builtin_amdgcn_mfma_f32_16x16x32_bf16(uf[1], xf0, z, 0, 0, 0);
        MAKE_XF(xfc, t1A, t1B);
    }
    block_sync();

    // stOwn from stx[0] (foreign tiles read at each body top)
    bf16x8 stOwn = *(const bf16x8*)&stx[0][((w + 0) & 3) * KT_STRIDE + fragoff];
    bf16x8 stf1, stf2, stf3;

    // ---- body tt: read state(tt) foreign; head = 4 reg MFMAs; foreign MFMAs;
    //      MAKE_XF(tt+2) + slot reload in the VALU shadow; pack -> write -> barrier ----
#define BODY(XA, XB, UU) do {                                                          \
    const int tt = t + (UU);                                                           \
    const short* rd_ = &stx[tt & 1][0];                                                \
    stf1 = *(const bf16x8*)&rd_[((w + 1) & 3) * KT_STRIDE + fragoff];                  \
    stf2 = *(const bf16x8*)&rd_[((w + 2) & 3) * KT_STRIDE + fragoff];                  \
    stf3 = *(const bf16x8*)&rd_[((w + 3) & 3) * KT_STRIDE + fragoff];                  \
    f32x4 z_ = {0.f, 0.f, 0.f, 0.f};                                                   \
    /* head: register-only MFMAs cover the stf read latency */                         \
    f32x4 c0a = __builtin_amdgcn_mfma_f32_16x16x32_bf16(wf[0][0], stOwn, accU0, 0, 0, 0); \
    f32x4 c1a = __builtin_amdgcn_mfma_f32_16x16x32_bf16(wf[1][0], stOwn, accU1, 0, 0, 0); \
    f32x4 nU0 = __builtin_amdgcn_mfma_f32_16x16x32_bf16(uf[0], xfc, z_, 0, 0, 0);      \
    f32x4 nU1 = __builtin_amdgcn_mfma_f32_16x16x32_bf16(uf[1], xfc, z_, 0, 0, 0);      \
    /* foreign MFMAs */                                                                \
    c0a = __builtin_amdgcn_mfma_f32_16x16x32_bf16(wf[0][1], stf1, c0a, 0, 0, 0);       \
    c1a = __builtin_amdgcn_mfma_f32_16x16x32_bf16(wf[1][1], stf1, c1a, 0, 0, 0);       \
    f32x4 c0b = __builtin_amdgcn_mfma_f32_16x16x32_bf16(wf[0][2], stf2, z_, 0, 0, 0);  \
    f32x4 c1b = __builtin_amdgcn_mfma_f32_16x16x32_bf16(wf[1][2], stf2, z_, 0, 0, 0);  \
    c0b = __builtin_amdgcn_mfma_f32_16x16x32_bf16(wf[0][3], stf3, c0b, 0, 0, 0);       \
    c1b = __builtin_amdgcn_mfma_f32_16x16x32_bf16(wf[1][3], stf3, c1b, 0, 0, 0);       \
    /* VALU shadow: build xf(tt+2), reload slot with x(tt+6) */                        \
    MAKE_XF(xfc, XA, XB);                                                              \
    {                                                                                  \
        const int s2_ = (tt + 6 < L_SEQ) ? (tt + 6) : (L_SEQ - 1);                     \
        XA = *(const float4*)(xpA + (size_t)s2_ * N_IN);                               \
        XB = *(const float4*)(xpB + (size_t)s2_ * N_IN);                               \
    }                                                                                  \
    accU0 = nU0; accU1 = nU1;                                                          \
    /* pack state(tt+1) own tile, write, sync */                                       \
    union { unsigned uu[4]; bf16x8 v; } su;                                            \
    su.uu[0] = cvtpk(fmaxf(c0a[0] + c0b[0], 0.f), fmaxf(c0a[1] + c0b[1], 0.f));        \
    su.uu[1] = cvtpk(fmaxf(c0a[2] + c0b[2], 0.f), fmaxf(c0a[3] + c0b[3], 0.f));        \
    su.uu[2] = cvtpk(fmaxf(c1a[0] + c1b[0], 0.f), fmaxf(c1a[1] + c1b[1], 0.f));        \
    su.uu[3] = cvtpk(fmaxf(c1a[2] + c1b[2], 0.f), fmaxf(c1a[3] + c1b[3], 0.f));        \
    stOwn = su.v;                                                                      \
    *(bf16x8*)&stx[(tt + 1) & 1][w * KT_STRIDE + fragoff] = stOwn;                     \
    block_sync();                                                                      \
} while (0)

    for (int t = 0; t < L_SEQ; t += 4) {
        BODY(xa2, xb2, 0);
        BODY(xa3, xb3, 1);
        BODY(xa0, xb0, 2);
        BODY(xa1, xb1, 3);
    }
#undef BODY
#undef MAKE_XF

    // ---- epilogue: yT = V^T @ aT_L + V_b.  Wave 0 (its li order == physical kt).
    //      Final state is in stx[L_SEQ & 1] == stx[0]. ----
    if (w == 0) {
        const short* rd = &stx[0][0];
        stf1 = *(const bf16x8*)&rd[1 * KT_STRIDE + fragoff];
        stf2 = *(const bf16x8*)&rd[2 * KT_STRIDE + fragoff];
        stf3 = *(const bf16x8*)&rd[3 * KT_STRIDE + fragoff];
        f32x4 acc = {0.f, 0.f, 0.f, 0.f};
        #pragma unroll
        for (int li = 0; li < 4; ++li) {
            bf16x8 vf;
            #pragma unroll
            for (int j = 0; j < 8; ++j)
                vf[j] = (n < M_OUT)
                      ? f2bf(V_w[(size_t)s_perm(li, q, j) * M_OUT + n])
                      : (short)0;
            const bf16x8 stt = (li == 0) ? stOwn : (li == 1) ? stf1 : (li == 2) ? stf2 : stf3;
            acc = __builtin_amdgcn_mfma_f32_16x16x32_bf16(vf, stt, acc, 0, 0, 0);
        }
        #pragma unroll
        for (int j = 0; j < 4; ++j) {
            const int m = 4 * q + j;
            if (m < M_OUT)
                out[(size_t)row * M_OUT + m] = acc[j] + V_b[m];
        }
    }
}

extern "C" void kernel_launch(void* const* d_in, const int* in_sizes, int n_in,
                              void* d_out, int out_size, void* d_ws, size_t ws_size,
                              hipStream_t stream) {
    const float* x   = (const float*)d_in[0];
    const float* a0  = (const float*)d_in[1];
    const float* U_w = (const float*)d_in[2];
    const float* U_b = (const float*)d_in[3];
    const float* W_w = (const float*)d_in[4];
    const float* W_b = (const float*)d_in[5];
    const float* V_w = (const float*)d_in[6];
    const float* V_b = (const float*)d_in[7];
    float* out = (float*)d_out;

    hipLaunchKernelGGL(elman_kernel, dim3(4096 / 16), dim3(256), 0, stream,
                       x, a0, U_w, U_b, W_w, W_b, V_w, V_b, out);
}

// Round 14
// 120.004 us; speedup vs baseline: 1.7812x; 1.2166x over previous
//
#include <hip/hip_runtime.h>
#include <hip/hip_bf16.h>

typedef __attribute__((ext_vector_type(8))) short bf16x8;
typedef __attribute__((ext_vector_type(4))) float f32x4;

#define L_SEQ 512
#define N_IN 12
#define S_DIM 128
#define M_OUT 12
#define LPAD 40           // shorts per n-row (80B -> <=2-way banks)
#define KT_STRIDE (16*LPAD)

// RNE f32->bf16 (cold paths)
__device__ inline short f2bf(float f) {
    union { float f; unsigned u; } q; q.f = f;
    unsigned r = (q.u + 0x7fffu + ((q.u >> 16) & 1u)) >> 16;
    return (short)r;
}
// packed f32x2 -> 2xbf16 (RNE), one VALU op
__device__ inline unsigned cvtpk(float lo, float hi) {
    unsigned r;
    asm("v_cvt_pk_bf16_f32 %0, %1, %2" : "=v"(r) : "v"(lo), "v"(hi));
    return r;
}
// B-slot (kt,q,j) holds state row s = 32kt + 16(j>>2) + 4q + (j&3).
// Same-lane D->B chaining: E2E-verified R4/R5/R7/R8/R11.
__device__ inline int s_perm(int kt, int q, int j) {
    return 32 * kt + 16 * (j >> 2) + 4 * q + (j & 3);
}
// lgkm-only barrier: does NOT drain vmcnt (helpers' x prefetch stays in flight)
__device__ inline void block_sync() {
    asm volatile("s_waitcnt lgkmcnt(0)" ::: "memory");
    __builtin_amdgcn_s_barrier();
}

__global__ __launch_bounds__(512, 1)
void elman_kernel(const float* __restrict__ x,
                  const float* __restrict__ a0,
                  const float* __restrict__ U_w,
                  const float* __restrict__ U_b,
                  const float* __restrict__ W_w,
                  const float* __restrict__ W_b,
                  const float* __restrict__ V_w,
                  const float* __restrict__ V_b,
                  float* __restrict__ out)
{
    __shared__ __align__(16) short stx[2][4 * KT_STRIDE];  // state exchange (ping-pong)
    __shared__ __align__(16) short xr[4][64 * 8];          // xf fragment ring (slot = t&3)

    const int tid  = threadIdx.x;
    const int w    = tid >> 6;        // waves 0..3 compute, 4..7 x-stage helpers
    const int l    = tid & 63;
    const int n    = l & 15;
    const int q    = l >> 4;
    const bool qodd = (q & 1);
    const int b0   = blockIdx.x * 16;
    const int row  = b0 + n;
    const int fragoff = n * LPAD + q * 8;
    const int h    = w & 3;           // helper id

    const float* xpA = x + (size_t)row * L_SEQ * N_IN + (q & 1) * 8;
    const float* xpB = xpA + (qodd ? 0 : 4);

#define MAKE_XF(XF, XA, XB) do {                                                       \
    union { unsigned uu[4]; bf16x8 v; } xu_;                                           \
    xu_.uu[0] = cvtpk(XA.x, XA.y);                                                     \
    xu_.uu[1] = cvtpk(XA.z, XA.w);                                                     \
    xu_.uu[2] = qodd ? 0x00003F80u : cvtpk(XB.x, XB.y);  /* k==12 -> bf16(1.0) */      \
    xu_.uu[3] = qodd ? 0u          : cvtpk(XB.z, XB.w);                                \
    XF = xu_.v;                                                                        \
} while (0)

    // ---- step-invariant fragments (compute waves) ----
    bf16x8 wf[2][4]; bf16x8 uf[2];
    if (w < 4) {
        #pragma unroll
        for (int hh = 0; hh < 2; ++hh) {
            const int c = (2 * w + hh) * 16 + n;
            #pragma unroll
            for (int li = 0; li < 4; ++li) {
                const int kt = (w + li) & 3;
                #pragma unroll
                for (int j = 0; j < 8; ++j)
                    wf[hh][li][j] = f2bf(W_w[(size_t)s_perm(kt, q, j) * S_DIM + c]);
            }
            #pragma unroll
            for (int j = 0; j < 8; ++j) {
                const int k = q * 8 + j;
                float v;
                if (k < N_IN)       v = U_w[(size_t)k * S_DIM + c];
                else if (k == N_IN) v = W_b[c] + U_b[c];   // bias via x-slot k=12 == 1.0
                else                v = 0.f;
                uf[hh][j] = f2bf(v);
            }
        }
    }

    // ---- stage a0 into stx[0] (exchange layout) ----
    for (int idx = tid; idx < 4 * 16 * 32; idx += 512) {
        const int kt = idx >> 9, r = (idx >> 5) & 15, qj = idx & 31;
        const int s = s_perm(kt, qj >> 3, qj & 7);
        stx[0][kt * KT_STRIDE + r * LPAD + qj] = f2bf(a0[(size_t)(b0 + r) * S_DIM + s]);
    }

    // ---- helper prologue (identical to R11): prestage xf(0..2); helper h's
    //      in-flight pair inits to x( h==3 ? 3 : h+4 ). ----
    float4 pA, pB;
    if (w >= 4) {
        if (h < 3) {
            float4 sa = *(const float4*)(xpA + (size_t)h * N_IN);
            float4 sb = *(const float4*)(xpB + (size_t)h * N_IN);
            bf16x8 xf; MAKE_XF(xf, sa, sb);
            *(bf16x8*)&xr[h][l * 8] = xf;
        }
        const int t0 = (h == 3) ? 3 : (h + 4);
        pA = *(const float4*)(xpA + (size_t)t0 * N_IN);
        pB = *(const float4*)(xpB + (size_t)t0 * N_IN);
    }
    block_sync();

    // ---- compute prologue: state(0) own tile, accU(0), xfc_cur = xf(1) ----
    bf16x8 stOwn, stf1, stf2, stf3, xfc_cur, xfc_next;
    f32x4 accU0, accU1;
    if (w < 4) {
        stOwn = *(const bf16x8*)&stx[0][((w + 0) & 3) * KT_STRIDE + fragoff];
        bf16x8 xf0 = *(const bf16x8*)&xr[0][l * 8];
        xfc_cur    = *(const bf16x8*)&xr[1][l * 8];
        f32x4 z = {0.f, 0.f, 0.f, 0.f};
        accU0 = __builtin_amdgcn_mfma_f32_16x16x32_bf16(uf[0], xf0, z, 0, 0, 0);
        accU1 = __builtin_amdgcn_mfma_f32_16x16x32_bf16(uf[1], xf0, z, 0, 0, 0);
    }

    // ---- body tt: ALL reads at top; head = 4 register-operand MFMAs; first
    //      foreign consumer at MFMA #5 (read->use ~100cyc, covered). ----
#define BODY(UU) do {                                                                  \
    const int tt = t + (UU);                                                           \
    if (w < 4) {                                                                       \
        const short* rd_ = &stx[tt & 1][0];                                            \
        stf1 = *(const bf16x8*)&rd_[((w + 1) & 3) * KT_STRIDE + fragoff];              \
        stf2 = *(const bf16x8*)&rd_[((w + 2) & 3) * KT_STRIDE + fragoff];              \
        stf3 = *(const bf16x8*)&rd_[((w + 3) & 3) * KT_STRIDE + fragoff];              \
        xfc_next = *(const bf16x8*)&xr[(tt + 2) & 3][l * 8];                           \
        __builtin_amdgcn_s_setprio(1);                                                 \
        f32x4 z_ = {0.f, 0.f, 0.f, 0.f};                                               \
        /* #1-4: register-operand MFMAs (cover the reads above) */                     \
        f32x4 nU0 = __builtin_amdgcn_mfma_f32_16x16x32_bf16(uf[0], xfc_cur, z_, 0, 0, 0); \
        f32x4 nU1 = __builtin_amdgcn_mfma_f32_16x16x32_bf16(uf[1], xfc_cur, z_, 0, 0, 0); \
        f32x4 c0a = __builtin_amdgcn_mfma_f32_16x16x32_bf16(wf[0][0], stOwn, accU0, 0, 0, 0); \
        f32x4 c1a = __builtin_amdgcn_mfma_f32_16x16x32_bf16(wf[1][0], stOwn, accU1, 0, 0, 0); \
        /* #5-10: foreign-state MFMAs */                                               \
        c0a = __builtin_amdgcn_mfma_f32_16x16x32_bf16(wf[0][1], stf1, c0a, 0, 0, 0);   \
        c1a = __builtin_amdgcn_mfma_f32_16x16x32_bf16(wf[1][1], stf1, c1a, 0, 0, 0);   \
        f32x4 c0b = __builtin_amdgcn_mfma_f32_16x16x32_bf16(wf[0][2], stf2, z_, 0, 0, 0); \
        f32x4 c1b = __builtin_amdgcn_mfma_f32_16x16x32_bf16(wf[1][2], stf2, z_, 0, 0, 0); \
        c0b = __builtin_amdgcn_mfma_f32_16x16x32_bf16(wf[0][3], stf3, c0b, 0, 0, 0);   \
        c1b = __builtin_amdgcn_mfma_f32_16x16x32_bf16(wf[1][3], stf3, c1b, 0, 0, 0);   \
        /* pack state(tt+1), write, rotate regs */                                     \
        union { unsigned uu[4]; bf16x8 v; } su;                                        \
        su.uu[0] = cvtpk(fmaxf(c0a[0] + c0b[0], 0.f), fmaxf(c0a[1] + c0b[1], 0.f));    \
        su.uu[1] = cvtpk(fmaxf(c0a[2] + c0b[2], 0.f), fmaxf(c0a[3] + c0b[3], 0.f));    \
        su.uu[2] = cvtpk(fmaxf(c1a[0] + c1b[0], 0.f), fmaxf(c1a[1] + c1b[1], 0.f));    \
        su.uu[3] = cvtpk(fmaxf(c1a[2] + c1b[2], 0.f), fmaxf(c1a[3] + c1b[3], 0.f));    \
        stOwn = su.v;                                                                  \
        *(bf16x8*)&stx[(tt + 1) & 1][w * KT_STRIDE + fragoff] = stOwn;                 \
        accU0 = nU0; accU1 = nU1;                                                      \
        xfc_cur = xfc_next;                                                            \
        __builtin_amdgcn_s_setprio(0);                                                 \
    } else {                                                                           \
        /* helper (UU+3)&3 stages xf(tt+3) from its pair, reloads x(tt+7) */           \
        if (h == (((UU) + 3) & 3)) {                                                   \
            bf16x8 xf_; MAKE_XF(xf_, pA, pB);                                          \
            *(bf16x8*)&xr[h][l * 8] = xf_;                                             \
            const int s2_ = (tt + 7 < L_SEQ) ? (tt + 7) : (L_SEQ - 1);                 \
            pA = *(const float4*)(xpA + (size_t)s2_ * N_IN);                           \
            pB = *(const float4*)(xpB + (size_t)s2_ * N_IN);                           \
        }                                                                              \
    }                                                                                  \
    block_sync();                                                                      \
} while (0)

    for (int t = 0; t < L_SEQ; t += 4) {
        BODY(0);
        BODY(1);
        BODY(2);
        BODY(3);
    }
#undef BODY
#undef MAKE_XF

    // ---- epilogue: yT = V^T @ aT_L + V_b.  Wave 0; final state in stx[0];
    //      wave 0's li order == physical kt. ----
    if (w == 0) {
        const short* rd = &stx[0][0];
        stf1 = *(const bf16x8*)&rd[1 * KT_STRIDE + fragoff];
        stf2 = *(const bf16x8*)&rd[2 * KT_STRIDE + fragoff];
        stf3 = *(const bf16x8*)&rd[3 * KT_STRIDE + fragoff];
        f32x4 acc = {0.f, 0.f, 0.f, 0.f};
        #pragma unroll
        for (int li = 0; li < 4; ++li) {
            bf16x8 vf;
            #pragma unroll
            for (int j = 0; j < 8; ++j)
                vf[j] = (n < M_OUT)
                      ? f2bf(V_w[(size_t)s_perm(li, q, j) * M_OUT + n])
                      : (short)0;
            const bf16x8 stt = (li == 0) ? stOwn : (li == 1) ? stf1 : (li == 2) ? stf2 : stf3;
            acc = __builtin_amdgcn_mfma_f32_16x16x32_bf16(vf, stt, acc, 0, 0, 0);
        }
        #pragma unroll
        for (int j = 0; j < 4; ++j) {
            const int m = 4 * q + j;
            if (m < M_OUT)
                out[(size_t)row * M_OUT + m] = acc[j] + V_b[m];
        }
    }
}

extern "C" void kernel_launch(void* const* d_in, const int* in_sizes, int n_in,
                              void* d_out, int out_size, void* d_ws, size_t ws_size,
                              hipStream_t stream) {
    const float* x   = (const float*)d_in[0];
    const float* a0  = (const float*)d_in[1];
    const float* U_w = (const float*)d_in[2];
    const float* U_b = (const float*)d_in[3];
    const float* W_w = (const float*)d_in[4];
    const float* W_b = (const float*)d_in[5];
    const float* V_w = (const float*)d_in[6];
    const float* V_b = (const float*)d_in[7];
    float* out = (float*)d_out;

    hipLaunchKernelGGL(elman_kernel, dim3(4096 / 16), dim3(512), 0, stream,
                       x, a0, U_w, U_b, W_w, W_b, V_w, V_b, out);
}

// Round 15
// 117.764 us; speedup vs baseline: 1.8150x; 1.0190x over previous
//
#include <hip/hip_runtime.h>
#include <hip/hip_bf16.h>

typedef __attribute__((ext_vector_type(8))) short bf16x8;
typedef __attribute__((ext_vector_type(4))) float f32x4;

#define L_SEQ 512
#define N_IN 12
#define S_DIM 128
#define M_OUT 12
#define LPAD 40           // shorts per n-row (80B -> <=2-way banks)
#define KT_STRIDE (16*LPAD)

// RNE f32->bf16 (cold paths)
__device__ inline short f2bf(float f) {
    union { float f; unsigned u; } q; q.f = f;
    unsigned r = (q.u + 0x7fffu + ((q.u >> 16) & 1u)) >> 16;
    return (short)r;
}
// packed f32x2 -> 2xbf16 (RNE), one VALU op
__device__ inline unsigned cvtpk(float lo, float hi) {
    unsigned r;
    asm("v_cvt_pk_bf16_f32 %0, %1, %2" : "=v"(r) : "v"(lo), "v"(hi));
    return r;
}
// B-slot (kt,q,j) holds state row s = 32kt + 16(j>>2) + 4q + (j&3).
// Same-lane D->B chaining: E2E-verified R4/R5/R7/R8/R11.
__device__ inline int s_perm(int kt, int q, int j) {
    return 32 * kt + 16 * (j >> 2) + 4 * q + (j & 3);
}
// lgkm-only barrier: does NOT drain vmcnt (helpers' x prefetch stays in flight)
__device__ inline void block_sync() {
    asm volatile("s_waitcnt lgkmcnt(0)" ::: "memory");
    __builtin_amdgcn_s_barrier();
}

__global__ __launch_bounds__(512, 1)
void elman_kernel(const float* __restrict__ x,
                  const float* __restrict__ a0,
                  const float* __restrict__ U_w,
                  const float* __restrict__ U_b,
                  const float* __restrict__ W_w,
                  const float* __restrict__ W_b,
                  const float* __restrict__ V_w,
                  const float* __restrict__ V_b,
                  float* __restrict__ out)
{
    __shared__ __align__(16) short stx[2][4 * KT_STRIDE];  // state exchange (ping-pong)
    __shared__ __align__(16) short xr[4][64 * 8];          // xf fragment ring (slot = t&3)

    const int tid  = threadIdx.x;
    const int w    = tid >> 6;        // waves 0..3 compute, 4..7 x-stage helpers
    const int l    = tid & 63;
    const int n    = l & 15;
    const int q    = l >> 4;
    const bool qodd = (q & 1);
    const int b0   = blockIdx.x * 16;
    const int row  = b0 + n;
    const int fragoff = n * LPAD + q * 8;
    const int h    = w & 3;           // helper id

    const float* xpA = x + (size_t)row * L_SEQ * N_IN + (q & 1) * 8;
    const float* xpB = xpA + (qodd ? 0 : 4);

#define MAKE_XF(XF, XA, XB) do {                                                       \
    union { unsigned uu[4]; bf16x8 v; } xu_;                                           \
    xu_.uu[0] = cvtpk(XA.x, XA.y);                                                     \
    xu_.uu[1] = cvtpk(XA.z, XA.w);                                                     \
    xu_.uu[2] = qodd ? 0x00003F80u : cvtpk(XB.x, XB.y);  /* k==12 -> bf16(1.0) */      \
    xu_.uu[3] = qodd ? 0u          : cvtpk(XB.z, XB.w);                                \
    XF = xu_.v;                                                                        \
} while (0)

    // ---- step-invariant fragments ----
    bf16x8 wf[2][4]; bf16x8 uf[2];
    if (w < 4) {
        #pragma unroll
        for (int hh = 0; hh < 2; ++hh) {
            const int c = (2 * w + hh) * 16 + n;
            #pragma unroll
            for (int li = 0; li < 4; ++li) {
                const int kt = (w + li) & 3;
                #pragma unroll
                for (int j = 0; j < 8; ++j)
                    wf[hh][li][j] = f2bf(W_w[(size_t)s_perm(kt, q, j) * S_DIM + c]);
            }
            #pragma unroll
            for (int j = 0; j < 8; ++j) {
                const int k = q * 8 + j;
                float v;
                if (k < N_IN)       v = U_w[(size_t)k * S_DIM + c];
                else if (k == N_IN) v = W_b[c] + U_b[c];   // bias via x-slot k=12 == 1.0
                else                v = 0.f;
                uf[hh][j] = f2bf(v);
            }
        }
    }

    // ---- stage a0 into stx[0] (exchange layout) ----
    for (int idx = tid; idx < 4 * 16 * 32; idx += 512) {
        const int kt = idx >> 9, r = (idx >> 5) & 15, qj = idx & 31;
        const int s = s_perm(kt, qj >> 3, qj & 7);
        stx[0][kt * KT_STRIDE + r * LPAD + qj] = f2bf(a0[(size_t)(b0 + r) * S_DIM + s]);
    }

    // ---- helper prologue ----
    // helper h owns xf slots with t' == h (mod 4); active at loop phase UU=(h+1)&3,
    // staging xf(tt+3) each activation. Pair init: x( h==3 ? 3 : h+4 ).
    // helpers 0,1,2 also prestage xf(0),xf(1),xf(2).
    float4 pA, pB;
    if (w >= 4) {
        if (h < 3) {
            float4 sa = *(const float4*)(xpA + (size_t)h * N_IN);
            float4 sb = *(const float4*)(xpB + (size_t)h * N_IN);
            bf16x8 xf; MAKE_XF(xf, sa, sb);
            *(bf16x8*)&xr[h][l * 8] = xf;
        }
        const int t0 = (h == 3) ? 3 : (h + 4);
        pA = *(const float4*)(xpA + (size_t)t0 * N_IN);
        pB = *(const float4*)(xpB + (size_t)t0 * N_IN);
    }
    block_sync();

    // ---- compute prologue: state(0), xf(0..2), accU(0), c_a(0) partial ----
    bf16x8 stOwnR, stf1, stf2, stf3, xfc_cur, xfc_next;
    f32x4 accU0, accU1, c0a, c1a;
    if (w < 4) {
        const short* rd = &stx[0][0];
        stOwnR = *(const bf16x8*)&rd[((w + 0) & 3) * KT_STRIDE + fragoff];
        stf1   = *(const bf16x8*)&rd[((w + 1) & 3) * KT_STRIDE + fragoff];
        stf2   = *(const bf16x8*)&rd[((w + 2) & 3) * KT_STRIDE + fragoff];
        stf3   = *(const bf16x8*)&rd[((w + 3) & 3) * KT_STRIDE + fragoff];
        bf16x8 xf0 = *(const bf16x8*)&xr[0][l * 8];
        xfc_cur    = *(const bf16x8*)&xr[1][l * 8];   // xf(1)
        xfc_next   = *(const bf16x8*)&xr[2][l * 8];   // xf(2)
        f32x4 z = {0.f, 0.f, 0.f, 0.f};
        accU0 = __builtin_amdgcn_mfma_f32_16x16x32_bf16(uf[0], xf0, z, 0, 0, 0);
        accU1 = __builtin_amdgcn_mfma_f32_16x16x32_bf16(uf[1], xf0, z, 0, 0, 0);
        c0a = __builtin_amdgcn_mfma_f32_16x16x32_bf16(wf[0][0], stOwnR, accU0, 0, 0, 0);
        c1a = __builtin_amdgcn_mfma_f32_16x16x32_bf16(wf[1][0], stOwnR, accU1, 0, 0, 0);
    }

    // ---- main recurrence.  body t: finish step t, pack state(t+1), pre-issue
    //      own MFMAs of step t+1; helpers stage xf(tt+3). ----
#define STEP(UU) do {                                                                  \
    const int tt = t + (UU);                                                           \
    if (w < 4) {                                                                       \
        __builtin_amdgcn_s_setprio(1);                                                 \
        f32x4 z = {0.f, 0.f, 0.f, 0.f};                                                \
        /* head: accU(tt+1) from xfc_cur = xf(tt+1) (read 1.5 epochs ago) */           \
        accU0 = __builtin_amdgcn_mfma_f32_16x16x32_bf16(uf[0], xfc_cur, z, 0, 0, 0);   \
        accU1 = __builtin_amdgcn_mfma_f32_16x16x32_bf16(uf[1], xfc_cur, z, 0, 0, 0);   \
        /* finish step tt */                                                           \
        c0a = __builtin_amdgcn_mfma_f32_16x16x32_bf16(wf[0][1], stf1, c0a, 0, 0, 0);   \
        c1a = __builtin_amdgcn_mfma_f32_16x16x32_bf16(wf[1][1], stf1, c1a, 0, 0, 0);   \
        f32x4 c0b = __builtin_amdgcn_mfma_f32_16x16x32_bf16(wf[0][2], stf2, z, 0, 0, 0); \
        f32x4 c1b = __builtin_amdgcn_mfma_f32_16x16x32_bf16(wf[1][2], stf2, z, 0, 0, 0); \
        c0b = __builtin_amdgcn_mfma_f32_16x16x32_bf16(wf[0][3], stf3, c0b, 0, 0, 0);   \
        c1b = __builtin_amdgcn_mfma_f32_16x16x32_bf16(wf[1][3], stf3, c1b, 0, 0, 0);   \
        /* pack state(tt+1) */                                                         \
        union { unsigned uu[4]; bf16x8 v; } su;                                        \
        su.uu[0] = cvtpk(fmaxf(c0a[0] + c0b[0], 0.f), fmaxf(c0a[1] + c0b[1], 0.f));    \
        su.uu[1] = cvtpk(fmaxf(c0a[2] + c0b[2], 0.f), fmaxf(c0a[3] + c0b[3], 0.f));    \
        su.uu[2] = cvtpk(fmaxf(c1a[0] + c1b[0], 0.f), fmaxf(c1a[1] + c1b[1], 0.f));    \
        su.uu[3] = cvtpk(fmaxf(c1a[2] + c1b[2], 0.f), fmaxf(c1a[3] + c1b[3], 0.f));    \
        stOwnR = su.v;                                                                 \
        /* pre-barrier: own-tile MFMAs of step tt+1 (all-register operands) */         \
        c0a = __builtin_amdgcn_mfma_f32_16x16x32_bf16(wf[0][0], stOwnR, accU0, 0, 0, 0); \
        c1a = __builtin_amdgcn_mfma_f32_16x16x32_bf16(wf[1][0], stOwnR, accU1, 0, 0, 0); \
        *(bf16x8*)&stx[(tt + 1) & 1][w * KT_STRIDE + fragoff] = stOwnR;                \
        xfc_cur = xfc_next;                                                            \
        __builtin_amdgcn_s_setprio(0);                                                 \
    } else {                                                                           \
        /* helper (UU+3)&3 stages xf(tt+3) from its pair, reloads x(tt+7) */           \
        if (h == (((UU) + 3) & 3)) {                                                   \
            bf16x8 xf_; MAKE_XF(xf_, pA, pB);                                          \
            *(bf16x8*)&xr[h][l * 8] = xf_;                                             \
            const int s2_ = (tt + 7 < L_SEQ) ? (tt + 7) : (L_SEQ - 1);                 \
            pA = *(const float4*)(xpA + (size_t)s2_ * N_IN);                           \
            pB = *(const float4*)(xpB + (size_t)s2_ * N_IN);                           \
        }                                                                              \
    }                                                                                  \
    block_sync();                                                                      \
    if (w < 4) {                                                                       \
        const short* rd_ = &stx[(tt + 1) & 1][0];                                      \
        stf1 = *(const bf16x8*)&rd_[((w + 1) & 3) * KT_STRIDE + fragoff];              \
        stf2 = *(const bf16x8*)&rd_[((w + 2) & 3) * KT_STRIDE + fragoff];              \
        stf3 = *(const bf16x8*)&rd_[((w + 3) & 3) * KT_STRIDE + fragoff];              \
        xfc_next = *(const bf16x8*)&xr[(((UU) + 3) & 3)][l * 8];   /* xf(tt+3) */      \
    }                                                                                  \
} while (0)

    for (int t = 0; t < L_SEQ; t += 4) {
        STEP(0);
        STEP(1);
        STEP(2);
        STEP(3);
    }
#undef STEP
#undef MAKE_XF

    // ---- epilogue: yT = V^T @ aT_L + V_b.  Wave 0 (its li order == physical kt). ----
    if (w == 0) {
        f32x4 acc = {0.f, 0.f, 0.f, 0.f};
        #pragma unroll
        for (int li = 0; li < 4; ++li) {
            bf16x8 vf;
            #pragma unroll
            for (int j = 0; j < 8; ++j)
                vf[j] = (n < M_OUT)
                      ? f2bf(V_w[(size_t)s_perm(li, q, j) * M_OUT + n])
                      : (short)0;
            const bf16x8 stt = (li == 0) ? stOwnR : (li == 1) ? stf1 : (li == 2) ? stf2 : stf3;
            acc = __builtin_amdgcn_mfma_f32_16x16x32_bf16(vf, stt, acc, 0, 0, 0);
        }
        #pragma unroll
        for (int j = 0; j < 4; ++j) {
            const int m = 4 * q + j;
            if (m < M_OUT)
                out[(size_t)row * M_OUT + m] = acc[j] + V_b[m];
        }
    }
}

extern "C" void kernel_launch(void* const* d_in, const int* in_sizes, int n_in,
                              void* d_out, int out_size, void* d_ws, size_t ws_size,
                              hipStream_t stream) {
    const float* x   = (const float*)d_in[0];
    const float* a0  = (const float*)d_in[1];
    const float* U_w = (const float*)d_in[2];
    const float* U_b = (const float*)d_in[3];
    const float* W_w = (const float*)d_in[4];
    const float* W_b = (const float*)d_in[5];
    const float* V_w = (const float*)d_in[6];
    const float* V_b = (const float*)d_in[7];
    float* out = (float*)d_out;

    hipLaunchKernelGGL(elman_kernel, dim3(4096 / 16), dim3(512), 0, stream,
                       x, a0, U_w, U_b, W_w, W_b, V_w, V_b, out);
}